// Round 1
// baseline (52.031 us; speedup 1.0000x reference)
//
#include <hip/hip_runtime.h>

#define SEQ 128
#define SD 15

__global__ __launch_bounds__(128) void dba_kernel(const float* __restrict__ dba,
                                                  const float* __restrict__ gt,
                                                  float* __restrict__ out) {
    const int b = blockIdx.x;
    const int s = threadIdx.x;

    __shared__ float sx[SEQ], sy[SEQ], sz[SEQ];
    __shared__ float sdq[SEQ][4];
    __shared__ float sq[SEQ][4];

    // Load delta = dba[b, s, 0:7] * 0.1 as two float4s (row is 128B-aligned).
    const float* row = dba + ((size_t)b * SEQ + s) * 32;
    const float4 v0 = *reinterpret_cast<const float4*>(row);
    const float4 v1 = *reinterpret_cast<const float4*>(row + 4);
    const float d0 = v0.x * 0.1f, d1 = v0.y * 0.1f, d2 = v0.z * 0.1f;
    const float d3 = v0.w * 0.1f, d4 = v1.x * 0.1f, d5 = v1.y * 0.1f, d6 = v1.z * 0.1f;

    sx[s] = d0; sy[s] = d1; sz[s] = d2;
    sdq[s][0] = d3; sdq[s][1] = d4; sdq[s][2] = d5; sdq[s][3] = d6;
    __syncthreads();

    // Inclusive Hillis-Steele scan over positions (7 rounds).
    for (int off = 1; off < SEQ; off <<= 1) {
        float vx = 0.f, vy = 0.f, vz = 0.f;
        if (s >= off) { vx = sx[s - off]; vy = sy[s - off]; vz = sz[s - off]; }
        __syncthreads();
        if (s >= off) { sx[s] += vx; sy[s] += vy; sz[s] += vz; }
        __syncthreads();
    }

    // Serial quaternion scan (inherently sequential: normalize is nonlinear).
    if (s == 0) {
        const float* g = gt + (size_t)b * SEQ * SD;
        float q0 = g[3], q1 = g[4], q2 = g[5], q3 = g[6];
        sq[0][0] = q0; sq[0][1] = q1; sq[0][2] = q2; sq[0][3] = q3;
        for (int t = 1; t < SEQ; ++t) {
            q0 += sdq[t - 1][0];
            q1 += sdq[t - 1][1];
            q2 += sdq[t - 1][2];
            q3 += sdq[t - 1][3];
            const float inv = 1.0f / sqrtf(q0 * q0 + q1 * q1 + q2 * q2 + q3 * q3);
            q0 *= inv; q1 *= inv; q2 *= inv; q3 *= inv;
            sq[t][0] = q0; sq[t][1] = q1; sq[t][2] = q2; sq[t][3] = q3;
        }
    }
    __syncthreads();

    // init_pos broadcast load (same address across block -> cache broadcast).
    const float* g = gt + (size_t)b * SEQ * SD;
    const float px = g[0], py = g[1], pz = g[2];

    // Exclusive prefix = inclusive[s-1].
    float ex = 0.f, ey = 0.f, ez = 0.f;
    if (s > 0) { ex = sx[s - 1]; ey = sy[s - 1]; ez = sz[s - 1]; }

    float* o = out + ((size_t)b * SEQ + s) * SD;
    o[0] = px + ex;
    o[1] = py + ey;
    o[2] = pz + ez;
    o[3] = sq[s][0];
    o[4] = sq[s][1];
    o[5] = sq[s][2];
    o[6] = sq[s][3];
#pragma unroll
    for (int k = 7; k < SD; ++k) o[k] = 0.f;
}

extern "C" void kernel_launch(void* const* d_in, const int* in_sizes, int n_in,
                              void* d_out, int out_size, void* d_ws, size_t ws_size,
                              hipStream_t stream) {
    const float* dba = (const float*)d_in[0];      // (4096, 128, 32)
    // d_in[1] = imu_measurements — unused by the reference
    const float* gt  = (const float*)d_in[2];      // (4096, 128, 15)
    float* out = (float*)d_out;                    // (4096, 128, 15)

    const int B = in_sizes[0] / (SEQ * 32);
    dba_kernel<<<B, SEQ, 0, stream>>>(dba, gt, out);
}